// Round 1
// baseline (4669.904 us; speedup 1.0000x reference)
//
#include <hip/hip_runtime.h>

#define NROWS 32768
#define NCODES 8192
#define DIM 512

#define BM 64
#define BN 64
#define BK 16
#define NSPLIT 2
#define NT_PER (NCODES / (BN * NSPLIT))   // 64 column-tiles per block

// workspace layout (float offsets)
#define WS_S    0                          // [NROWS]  ||z_n||^2
#define WS_T    (WS_S + NROWS)             // [NCODES] ||e_k||^2
#define WS_BD   (WS_T + NCODES)            // [NSPLIT*NROWS] partial best d
#define WS_BI   (WS_BD + NSPLIT * NROWS)   // [NSPLIT*NROWS] partial best idx (int)
#define WS_LOSS (WS_BI + NSPLIT * NROWS)   // [1] loss accumulator

// ---------------------------------------------------------------- row norms
__global__ void vq_rownorm(const float* __restrict__ x, float* __restrict__ out,
                           int nrows) {
  int gid  = blockIdx.x * blockDim.x + threadIdx.x;
  int w    = gid >> 6;
  int lane = gid & 63;
  if (w >= nrows) return;
  const float4* row = (const float4*)(x + (size_t)w * DIM);
  float4 a = row[lane];
  float4 b = row[lane + 64];
  float s = a.x * a.x + a.y * a.y + a.z * a.z + a.w * a.w
          + b.x * b.x + b.y * b.y + b.z * b.z + b.w * b.w;
#pragma unroll
  for (int off = 32; off > 0; off >>= 1) s += __shfl_down(s, off);
  if (lane == 0) out[w] = s;
}

// ------------------------------------------------- fused GEMM + argmin tile
__global__ __launch_bounds__(256, 4) void vq_argmin(
    const float* __restrict__ z, const float* __restrict__ emb,
    const float* __restrict__ s_z, const float* __restrict__ t_e,
    float* __restrict__ best_d, int* __restrict__ best_i) {
  __shared__ float zs[BK][BM];   // k-major (transposed) tiles
  __shared__ float es[BK][BN];
  __shared__ float red_d[BM][16];
  __shared__ int   red_i[BM][16];

  const int tid  = threadIdx.x;
  const int tm   = tid >> 4;        // 0..15 -> rows tm*4..tm*4+3
  const int tn   = tid & 15;        // 0..15 -> cols tn*4..tn*4+3
  const int row0 = blockIdx.x * BM;
  const int cbase = blockIdx.y * (NT_PER * BN);

  // staging: thread t loads a float4 of row sr at k-offset sk
  const int sr = tid >> 2;          // 0..63
  const int sk = (tid & 3) << 2;    // 0,4,8,12

  float s_i[4];
#pragma unroll
  for (int i = 0; i < 4; ++i) s_i[i] = s_z[row0 + tm * 4 + i];

  float bd[4];
  int   bi[4];
#pragma unroll
  for (int i = 0; i < 4; ++i) { bd[i] = 3.0e38f; bi[i] = 0; }

  const float* zrow = z + (size_t)(row0 + sr) * DIM;

  for (int nt = 0; nt < NT_PER; ++nt) {
    const int col0 = cbase + nt * BN;
    const float* erow = emb + (size_t)(col0 + sr) * DIM;

    float acc[4][4];
#pragma unroll
    for (int i = 0; i < 4; ++i)
#pragma unroll
      for (int j = 0; j < 4; ++j) acc[i][j] = 0.0f;

    for (int kt = 0; kt < DIM; kt += BK) {
      float4 zv = *(const float4*)(zrow + kt + sk);
      float4 ev = *(const float4*)(erow + kt + sk);
      __syncthreads();  // protect previous tile's reads
      zs[sk + 0][sr] = zv.x; zs[sk + 1][sr] = zv.y;
      zs[sk + 2][sr] = zv.z; zs[sk + 3][sr] = zv.w;
      es[sk + 0][sr] = ev.x; es[sk + 1][sr] = ev.y;
      es[sk + 2][sr] = ev.z; es[sk + 3][sr] = ev.w;
      __syncthreads();
#pragma unroll
      for (int kk = 0; kk < BK; ++kk) {
        const float4 zq = *(const float4*)&zs[kk][tm * 4];
        const float4 eq = *(const float4*)&es[kk][tn * 4];
        acc[0][0] += zq.x * eq.x; acc[0][1] += zq.x * eq.y;
        acc[0][2] += zq.x * eq.z; acc[0][3] += zq.x * eq.w;
        acc[1][0] += zq.y * eq.x; acc[1][1] += zq.y * eq.y;
        acc[1][2] += zq.y * eq.z; acc[1][3] += zq.y * eq.w;
        acc[2][0] += zq.z * eq.x; acc[2][1] += zq.z * eq.y;
        acc[2][2] += zq.z * eq.z; acc[2][3] += zq.z * eq.w;
        acc[3][0] += zq.w * eq.x; acc[3][1] += zq.w * eq.y;
        acc[3][2] += zq.w * eq.z; acc[3][3] += zq.w * eq.w;
      }
    }

    // epilogue: d = (s + t) - 2*dot, replicating reference fp32 expression.
    // Ascending col scan + strict < keeps the FIRST minimizer (argmin tie rule).
#pragma unroll
    for (int j = 0; j < 4; ++j) {
      const int   cidx = col0 + tn * 4 + j;
      const float tj   = t_e[cidx];
#pragma unroll
      for (int i = 0; i < 4; ++i) {
        const float d = (s_i[i] + tj) - 2.0f * acc[i][j];
        if (d < bd[i]) { bd[i] = d; bi[i] = cidx; }
      }
    }
  }

  // cross-thread (16 col-groups) reduction per row
#pragma unroll
  for (int i = 0; i < 4; ++i) {
    red_d[tm * 4 + i][tn] = bd[i];
    red_i[tm * 4 + i][tn] = bi[i];
  }
  __syncthreads();
  if (tid < BM) {
    float d = red_d[tid][0];
    int  ix = red_i[tid][0];
#pragma unroll
    for (int t = 1; t < 16; ++t) {
      const float dd = red_d[tid][t];
      const int   ii = red_i[tid][t];
      if (dd < d || (dd == d && ii < ix)) { d = dd; ix = ii; }
    }
    best_d[blockIdx.y * NROWS + row0 + tid] = d;
    best_i[blockIdx.y * NROWS + row0 + tid] = ix;
  }
}

// ---------------------------------------- merge halves + gather + loss part
__global__ void vq_gather(const float* __restrict__ z, const float* __restrict__ emb,
                          const float* __restrict__ best_d, const int* __restrict__ best_i,
                          float* __restrict__ out, float* __restrict__ loss_acc) {
  const int gid  = blockIdx.x * blockDim.x + threadIdx.x;
  const int w    = gid >> 6;
  const int lane = gid & 63;
  const int nw   = (gridDim.x * blockDim.x) >> 6;

  float lsum = 0.0f;
  for (int row = w; row < NROWS; row += nw) {
    const float d0 = best_d[row];
    const float d1 = best_d[NROWS + row];
    const int   i0 = best_i[row];
    const int   i1 = best_i[NROWS + row];
    // half-0 indices are always smaller -> ties keep i0 (first occurrence)
    const int idx = (d1 < d0) ? i1 : i0;

    const float* er = emb + (size_t)idx * DIM;
    const float* zr = z + (size_t)row * DIM;
    float* orow = out + 1 + (size_t)row * DIM;  // offset 1 => scalar stores
#pragma unroll
    for (int c = 0; c < 8; ++c) {
      const float zv = zr[c * 64 + lane];
      const float evv = er[c * 64 + lane];
      const float dv = evv - zv;           // sg(z_q - z)
      orow[c * 64 + lane] = zv + dv;       // z + sg(z_q - z), reference rounding
      lsum += dv * dv;
    }
    if (lane == 0) out[1 + (size_t)NROWS * DIM + row] = (float)idx;
  }
#pragma unroll
  for (int off = 32; off > 0; off >>= 1) lsum += __shfl_down(lsum, off);
  if (lane == 0) atomicAdd(loss_acc, lsum);
}

__global__ void vq_finalize(const float* __restrict__ loss_acc,
                            float* __restrict__ out) {
  if (threadIdx.x == 0 && blockIdx.x == 0) {
    // mean over N*D = 2^24 (exact power-of-two divide); loss = m + BETA*m
    const float m = loss_acc[0] / 16777216.0f;
    out[0] = m + m;
  }
}

// --------------------------------------------------------------------------
extern "C" void kernel_launch(void* const* d_in, const int* in_sizes, int n_in,
                              void* d_out, int out_size, void* d_ws, size_t ws_size,
                              hipStream_t stream) {
  const float* z   = (const float*)d_in[0];
  const float* emb = (const float*)d_in[1];
  float* ws  = (float*)d_ws;
  float* out = (float*)d_out;

  float* s_z    = ws + WS_S;
  float* t_e    = ws + WS_T;
  float* bestd  = ws + WS_BD;
  int*   besti  = (int*)(ws + WS_BI);
  float* lossum = ws + WS_LOSS;

  hipMemsetAsync(lossum, 0, sizeof(float), stream);

  vq_rownorm<<<NROWS / 4, 256, 0, stream>>>(z, s_z, NROWS);
  vq_rownorm<<<NCODES / 4, 256, 0, stream>>>(emb, t_e, NCODES);

  vq_argmin<<<dim3(NROWS / BM, NSPLIT), 256, 0, stream>>>(z, emb, s_z, t_e,
                                                          bestd, besti);

  vq_gather<<<2048, 256, 0, stream>>>(z, emb, bestd, besti, out, lossum);
  vq_finalize<<<1, 64, 0, stream>>>(lossum, out);
}

// Round 2
// 1432.257 us; speedup vs baseline: 3.2605x; 3.2605x over previous
//
#include <hip/hip_runtime.h>

typedef unsigned short u16;
typedef __attribute__((ext_vector_type(8))) short short8;
typedef __attribute__((ext_vector_type(4))) float f32x4;
typedef __attribute__((ext_vector_type(8))) u16 u16x8;

#define NROWS 32768
#define NCODES 8192
#define DIM 512
#define KT (DIM / 32)            // 16 k-steps of 32

// ---- fast-path GEMM geometry
#define BM 128
#define BN 128
#define NSPLIT 8
#define NT (NCODES / NSPLIT / BN)  // 8 col tiles per block

// ---- fast-path ws byte offsets (fragment-ordered bf16 hi/lo buffers)
#define WB_ZHI ((size_t)0)
#define WB_ZLO (WB_ZHI + (size_t)NROWS * DIM * 2)
#define WB_EHI (WB_ZLO + (size_t)NROWS * DIM * 2)
#define WB_ELO (WB_EHI + (size_t)NCODES * DIM * 2)
#define WB_TE  (WB_ELO + (size_t)NCODES * DIM * 2)
#define WB_TOP2 (WB_TE + (size_t)NCODES * 4)
#define WB_LOSS (WB_TOP2 + (size_t)NSPLIT * NROWS * 16)
#define WB_NEED (WB_LOSS + 64)

// ---- fallback ws float offsets (round-1 layout)
#define FW_S    0
#define FW_T    (FW_S + NROWS)
#define FW_BD   (FW_T + NCODES)
#define FW_BI   (FW_BD + 2 * NROWS)
#define FW_LOSS (FW_BI + 2 * NROWS)

__device__ __forceinline__ u16 f2bf(float x) {
  unsigned u = __float_as_uint(x);
  u += 0x7FFFu + ((u >> 16) & 1u);   // RNE; inputs finite
  return (u16)(u >> 16);
}
__device__ __forceinline__ float bf2f(u16 h) {
  return __uint_as_float(((unsigned)h) << 16);
}
__device__ __forceinline__ void gld16(const void* g, void* l) {
  __builtin_amdgcn_global_load_lds(
      (const __attribute__((address_space(1))) void*)g,
      (__attribute__((address_space(3))) void*)l, 16, 0, 0);
}

// ---------------------------------------------------------------- row norms
__global__ void vq_rownorm(const float* __restrict__ x, float* __restrict__ out,
                           int nrows) {
  int gid  = blockIdx.x * blockDim.x + threadIdx.x;
  int w    = gid >> 6;
  int lane = gid & 63;
  if (w >= nrows) return;
  const float4* row = (const float4*)(x + (size_t)w * DIM);
  float4 a = row[lane];
  float4 b = row[lane + 64];
  float s = a.x * a.x + a.y * a.y + a.z * a.z + a.w * a.w
          + b.x * b.x + b.y * b.y + b.z * b.z + b.w * b.w;
#pragma unroll
  for (int off = 32; off > 0; off >>= 1) s += __shfl_down(s, off);
  if (lane == 0) out[w] = s;
}

// ------------------------------------------- split fp32 -> bf16 hi/lo chunks
// chunk layout: [g (16-row group)][kt][lane][8 bf16], lane = kgrp*16 + row%16
__global__ void vq_split(const float* __restrict__ x, u16* __restrict__ hi,
                         u16* __restrict__ lo, int nwaves) {
  int W = blockIdx.x * (blockDim.x >> 6) + (threadIdx.x >> 6);
  if (W >= nwaves) return;
  int lane = threadIdx.x & 63;
  int g = W >> 4, kt = W & (KT - 1);
  int row = g * 16 + (lane & 15);
  int k0  = kt * 32 + (lane >> 4) * 8;
  const float* src = x + (size_t)row * DIM + k0;
  f32x4 a = *(const f32x4*)src;
  f32x4 b = *(const f32x4*)(src + 4);
  float v[8] = {a[0], a[1], a[2], a[3], b[0], b[1], b[2], b[3]};
  u16x8 h, l;
#pragma unroll
  for (int j = 0; j < 8; ++j) {
    u16 hh = f2bf(v[j]);
    h[j] = hh;
    l[j] = f2bf(v[j] - bf2f(hh));   // residual exact in fp32
  }
  size_t off = ((size_t)W * 64 + lane) * 8;
  *(u16x8*)(hi + off) = h;
  *(u16x8*)(lo + off) = l;
}

// ------------------------------------- split-bf16 MFMA distance + top2 track
__global__ __launch_bounds__(256, 2) void vq_mfma_top2(
    const u16* __restrict__ zh, const u16* __restrict__ zl,
    const u16* __restrict__ eh, const u16* __restrict__ el,
    const float* __restrict__ te, f32x4* __restrict__ top2) {
  __shared__ __align__(16) u16 lds[16384];  // Ah|Al|Bh|Bl, 8KB each
  u16* Ah = lds;
  u16* Al = lds + 4096;
  u16* Bh = lds + 8192;
  u16* Bl = lds + 12288;

  const int tid  = threadIdx.x;
  const int w    = tid >> 6;
  const int lane = tid & 63;
  const int bm   = blockIdx.x;
  const int split = blockIdx.y;
  const int cb   = split * (NT * BN);

  const size_t laneoff = (size_t)lane * 8;
  const u16* pah = zh + (size_t)(bm * 8 + 2 * w) * 8192 + laneoff;
  const u16* pal = zl + (size_t)(bm * 8 + 2 * w) * 8192 + laneoff;
  u16* dAh0 = Ah + (2 * w) * 512; u16* dAh1 = dAh0 + 512;
  u16* dAl0 = Al + (2 * w) * 512; u16* dAl1 = dAl0 + 512;
  u16* dBh0 = Bh + (2 * w) * 512; u16* dBh1 = dBh0 + 512;
  u16* dBl0 = Bl + (2 * w) * 512; u16* dBl1 = dBl0 + 512;

  float bd1[8], bd2[8];
  int   bi1[8], bi2[8];
#pragma unroll
  for (int s = 0; s < 8; ++s) {
    bd1[s] = 3.0e38f; bd2[s] = 3.0e38f;
    bi1[s] = 0x7fffffff; bi2[s] = 0x7fffffff;
  }

  for (int nt = 0; nt < NT; ++nt) {
    const int col0 = cb + nt * BN;
    const u16* pbh = eh + (size_t)((col0 >> 4) + 2 * w) * 8192 + laneoff;
    const u16* pbl = el + (size_t)((col0 >> 4) + 2 * w) * 8192 + laneoff;

    f32x4 acc[2][8];
#pragma unroll
    for (int m = 0; m < 2; ++m)
#pragma unroll
      for (int n = 0; n < 8; ++n) acc[m][n] = (f32x4){0.f, 0.f, 0.f, 0.f};

    for (int kt = 0; kt < KT; ++kt) {
      const size_t ko = (size_t)kt * 512;
      __syncthreads();
      gld16(pah + ko, dAh0); gld16(pah + 8192 + ko, dAh1);
      gld16(pal + ko, dAl0); gld16(pal + 8192 + ko, dAl1);
      gld16(pbh + ko, dBh0); gld16(pbh + 8192 + ko, dBh1);
      gld16(pbl + ko, dBl0); gld16(pbl + 8192 + ko, dBl1);
      __syncthreads();

      const short8 ah0 = *(const short8*)(Ah + (2 * w) * 512 + lane * 8);
      const short8 ah1 = *(const short8*)(Ah + (2 * w + 1) * 512 + lane * 8);
      const short8 al0 = *(const short8*)(Al + (2 * w) * 512 + lane * 8);
      const short8 al1 = *(const short8*)(Al + (2 * w + 1) * 512 + lane * 8);
#pragma unroll
      for (int n = 0; n < 8; ++n) {
        const short8 bh = *(const short8*)(Bh + n * 512 + lane * 8);
        const short8 bl = *(const short8*)(Bl + n * 512 + lane * 8);
        acc[0][n] = __builtin_amdgcn_mfma_f32_16x16x32_bf16(ah0, bh, acc[0][n], 0, 0, 0);
        acc[0][n] = __builtin_amdgcn_mfma_f32_16x16x32_bf16(ah0, bl, acc[0][n], 0, 0, 0);
        acc[0][n] = __builtin_amdgcn_mfma_f32_16x16x32_bf16(al0, bh, acc[0][n], 0, 0, 0);
        acc[1][n] = __builtin_amdgcn_mfma_f32_16x16x32_bf16(ah1, bh, acc[1][n], 0, 0, 0);
        acc[1][n] = __builtin_amdgcn_mfma_f32_16x16x32_bf16(ah1, bl, acc[1][n], 0, 0, 0);
        acc[1][n] = __builtin_amdgcn_mfma_f32_16x16x32_bf16(al1, bh, acc[1][n], 0, 0, 0);
      }
    }

    // fold this col-tile into running top2 (order d', tie -> smaller idx;
    // s_row omitted: constant per row, irrelevant for ordering)
    float tval[8];
#pragma unroll
    for (int n = 0; n < 8; ++n) tval[n] = te[col0 + n * 16 + (lane & 15)];
#pragma unroll
    for (int m = 0; m < 2; ++m)
#pragma unroll
      for (int n = 0; n < 8; ++n) {
        const int c = col0 + n * 16 + (lane & 15);
#pragma unroll
        for (int q = 0; q < 4; ++q) {
          const float d = tval[n] - 2.0f * acc[m][n][q];
          const int s = m * 4 + q;
          if (d < bd1[s] || (d == bd1[s] && c < bi1[s])) {
            bd2[s] = bd1[s]; bi2[s] = bi1[s]; bd1[s] = d; bi1[s] = c;
          } else if (d < bd2[s] || (d == bd2[s] && c < bi2[s])) {
            bd2[s] = d; bi2[s] = c;
          }
        }
      }
  }

  // butterfly top2-merge across the 16 lanes sharing a row
#pragma unroll
  for (int s = 0; s < 8; ++s) {
#pragma unroll
    for (int st = 1; st < 16; st <<= 1) {
      const float od1 = __shfl_xor(bd1[s], st);
      const int   oi1 = __shfl_xor(bi1[s], st);
      const float od2 = __shfl_xor(bd2[s], st);
      const int   oi2 = __shfl_xor(bi2[s], st);
      const bool o1_lt = (od1 < bd1[s]) || (od1 == bd1[s] && oi1 < bi1[s]);
      if (o1_lt) {
        const bool old1_lt_o2 = (bd1[s] < od2) || (bd1[s] == od2 && bi1[s] < oi2);
        if (old1_lt_o2) { bd2[s] = bd1[s]; bi2[s] = bi1[s]; }
        else            { bd2[s] = od2;    bi2[s] = oi2; }
        bd1[s] = od1; bi1[s] = oi1;
      } else if ((od1 < bd2[s]) || (od1 == bd2[s] && oi1 < bi2[s])) {
        bd2[s] = od1; bi2[s] = oi1;
      }
    }
  }
  if ((lane & 15) == 0) {
    const int p = lane >> 4;
#pragma unroll
    for (int s = 0; s < 8; ++s) {
      const int m = s >> 2, q = s & 3;
      const int row = bm * BM + w * 32 + m * 16 + p * 4 + q;
      f32x4 v;
      v[0] = bd1[s]; v[1] = __int_as_float(bi1[s]);
      v[2] = bd2[s]; v[3] = __int_as_float(bi2[s]);
      top2[(size_t)split * NROWS + row] = v;
    }
  }
}

// ---------------- merge splits + exact fp32 rescore of top2 + gather + loss
__global__ void vq_rescore_out(const float* __restrict__ z, const float* __restrict__ emb,
                               const float* __restrict__ te, const f32x4* __restrict__ top2,
                               float* __restrict__ out, float* __restrict__ loss_acc) {
  const int row  = (blockIdx.x * blockDim.x + threadIdx.x) >> 6;
  const int lane = threadIdx.x & 63;
  if (row >= NROWS) return;

  float d1 = 3.0e38f, d2 = 3.0e38f;
  int   i1 = 0x7fffffff, i2 = 0x7fffffff;
#pragma unroll
  for (int s = 0; s < NSPLIT; ++s) {
    const f32x4 t = top2[(size_t)s * NROWS + row];
    const float ad1 = t[0]; const int ai1 = __float_as_int(t[1]);
    const float ad2 = t[2]; const int ai2 = __float_as_int(t[3]);
    const bool a1_lt = (ad1 < d1) || (ad1 == d1 && ai1 < i1);
    if (a1_lt) {
      const bool old_lt = (d1 < ad2) || (d1 == ad2 && i1 < ai2);
      if (old_lt) { d2 = d1; i2 = i1; } else { d2 = ad2; i2 = ai2; }
      d1 = ad1; i1 = ai1;
    } else if ((ad1 < d2) || (ad1 == d2 && ai1 < i2)) { d2 = ad1; i2 = ai1; }
  }

  const f32x4* zr  = (const f32x4*)(z + (size_t)row * DIM);
  const f32x4* e1r = (const f32x4*)(emb + (size_t)i1 * DIM);
  const f32x4* e2r = (const f32x4*)(emb + (size_t)i2 * DIM);
  const f32x4 za = zr[lane],  zb = zr[lane + 64];
  const f32x4 ea1 = e1r[lane], eb1 = e1r[lane + 64];
  const f32x4 ea2 = e2r[lane], eb2 = e2r[lane + 64];

  float sp = za[0] * za[0] + za[1] * za[1] + za[2] * za[2] + za[3] * za[3]
           + zb[0] * zb[0] + zb[1] * zb[1] + zb[2] * zb[2] + zb[3] * zb[3];
  float p1 = za[0] * ea1[0] + za[1] * ea1[1] + za[2] * ea1[2] + za[3] * ea1[3]
           + zb[0] * eb1[0] + zb[1] * eb1[1] + zb[2] * eb1[2] + zb[3] * eb1[3];
  float p2 = za[0] * ea2[0] + za[1] * ea2[1] + za[2] * ea2[2] + za[3] * ea2[3]
           + zb[0] * eb2[0] + zb[1] * eb2[1] + zb[2] * eb2[2] + zb[3] * eb2[3];
#pragma unroll
  for (int off = 32; off > 0; off >>= 1) {
    sp += __shfl_down(sp, off);
    p1 += __shfl_down(p1, off);
    p2 += __shfl_down(p2, off);
  }
  sp = __shfl(sp, 0); p1 = __shfl(p1, 0); p2 = __shfl(p2, 0);

  const float d1e = (sp + te[i1]) - 2.0f * p1;
  const float d2e = (sp + te[i2]) - 2.0f * p2;
  const bool pick2 = (d2e < d1e) || (d2e == d1e && i2 < i1);
  const int  widx  = pick2 ? i2 : i1;
  const f32x4 ga = pick2 ? ea2 : ea1;
  const f32x4 gb = pick2 ? eb2 : eb1;

  float* orow = out + 1 + (size_t)row * DIM;
  float lsum = 0.f;
#pragma unroll
  for (int j = 0; j < 4; ++j) {
    const float dv = ga[j] - za[j];
    orow[4 * lane + j] = za[j] + dv;
    lsum += dv * dv;
    const float dw = gb[j] - zb[j];
    orow[256 + 4 * lane + j] = zb[j] + dw;
    lsum += dw * dw;
  }
#pragma unroll
  for (int off = 32; off > 0; off >>= 1) lsum += __shfl_down(lsum, off);
  if (lane == 0) {
    atomicAdd(loss_acc, lsum);
    out[1 + (size_t)NROWS * DIM + row] = (float)widx;
  }
}

__global__ void vq_finalize(const float* __restrict__ loss_acc,
                            float* __restrict__ out) {
  if (threadIdx.x == 0 && blockIdx.x == 0) {
    const float m = loss_acc[0] / 16777216.0f;  // mean over N*D = 2^24
    out[0] = m + m;                             // (1 + BETA) * m
  }
}

// ======================= fallback: round-1 fp32 path =======================
__global__ __launch_bounds__(256, 4) void vq_argmin_fb(
    const float* __restrict__ z, const float* __restrict__ emb,
    const float* __restrict__ s_z, const float* __restrict__ t_e,
    float* __restrict__ best_d, int* __restrict__ best_i) {
  __shared__ float zs[16][64];
  __shared__ float es[16][64];
  __shared__ float red_d[64][16];
  __shared__ int   red_i[64][16];

  const int tid = threadIdx.x;
  const int tm = tid >> 4, tn = tid & 15;
  const int row0 = blockIdx.x * 64;
  const int cbase = blockIdx.y * (64 * 64);
  const int sr = tid >> 2, sk = (tid & 3) << 2;

  float s_i[4];
#pragma unroll
  for (int i = 0; i < 4; ++i) s_i[i] = s_z[row0 + tm * 4 + i];
  float bd[4]; int bi[4];
#pragma unroll
  for (int i = 0; i < 4; ++i) { bd[i] = 3.0e38f; bi[i] = 0; }
  const float* zrow = z + (size_t)(row0 + sr) * DIM;

  for (int nt = 0; nt < 64; ++nt) {
    const int col0 = cbase + nt * 64;
    const float* erow = emb + (size_t)(col0 + sr) * DIM;
    float acc[4][4];
#pragma unroll
    for (int i = 0; i < 4; ++i)
#pragma unroll
      for (int j = 0; j < 4; ++j) acc[i][j] = 0.0f;

    for (int kt = 0; kt < DIM; kt += 16) {
      float4 zv = *(const float4*)(zrow + kt + sk);
      float4 ev = *(const float4*)(erow + kt + sk);
      __syncthreads();
      zs[sk + 0][sr] = zv.x; zs[sk + 1][sr] = zv.y;
      zs[sk + 2][sr] = zv.z; zs[sk + 3][sr] = zv.w;
      es[sk + 0][sr] = ev.x; es[sk + 1][sr] = ev.y;
      es[sk + 2][sr] = ev.z; es[sk + 3][sr] = ev.w;
      __syncthreads();
#pragma unroll
      for (int kk = 0; kk < 16; ++kk) {
        const float4 zq = *(const float4*)&zs[kk][tm * 4];
        const float4 eq = *(const float4*)&es[kk][tn * 4];
        acc[0][0] += zq.x * eq.x; acc[0][1] += zq.x * eq.y;
        acc[0][2] += zq.x * eq.z; acc[0][3] += zq.x * eq.w;
        acc[1][0] += zq.y * eq.x; acc[1][1] += zq.y * eq.y;
        acc[1][2] += zq.y * eq.z; acc[1][3] += zq.y * eq.w;
        acc[2][0] += zq.z * eq.x; acc[2][1] += zq.z * eq.y;
        acc[2][2] += zq.z * eq.z; acc[2][3] += zq.z * eq.w;
        acc[3][0] += zq.w * eq.x; acc[3][1] += zq.w * eq.y;
        acc[3][2] += zq.w * eq.z; acc[3][3] += zq.w * eq.w;
      }
    }
#pragma unroll
    for (int j = 0; j < 4; ++j) {
      const int cidx = col0 + tn * 4 + j;
      const float tj = t_e[cidx];
#pragma unroll
      for (int i = 0; i < 4; ++i) {
        const float d = (s_i[i] + tj) - 2.0f * acc[i][j];
        if (d < bd[i]) { bd[i] = d; bi[i] = cidx; }
      }
    }
  }
#pragma unroll
  for (int i = 0; i < 4; ++i) {
    red_d[tm * 4 + i][tn] = bd[i];
    red_i[tm * 4 + i][tn] = bi[i];
  }
  __syncthreads();
  if (tid < 64) {
    float d = red_d[tid][0];
    int ix = red_i[tid][0];
#pragma unroll
    for (int t = 1; t < 16; ++t) {
      const float dd = red_d[tid][t];
      const int ii = red_i[tid][t];
      if (dd < d || (dd == d && ii < ix)) { d = dd; ix = ii; }
    }
    best_d[blockIdx.y * NROWS + row0 + tid] = d;
    best_i[blockIdx.y * NROWS + row0 + tid] = ix;
  }
}

__global__ void vq_gather_fb(const float* __restrict__ z, const float* __restrict__ emb,
                             const float* __restrict__ best_d, const int* __restrict__ best_i,
                             float* __restrict__ out, float* __restrict__ loss_acc) {
  const int gid = blockIdx.x * blockDim.x + threadIdx.x;
  const int w = gid >> 6, lane = gid & 63;
  const int nw = (gridDim.x * blockDim.x) >> 6;
  float lsum = 0.0f;
  for (int row = w; row < NROWS; row += nw) {
    const float d0 = best_d[row], d1 = best_d[NROWS + row];
    const int i0 = best_i[row], i1v = best_i[NROWS + row];
    const int idx = (d1 < d0) ? i1v : i0;
    const float* er = emb + (size_t)idx * DIM;
    const float* zr = z + (size_t)row * DIM;
    float* orow = out + 1 + (size_t)row * DIM;
#pragma unroll
    for (int c = 0; c < 8; ++c) {
      const float zv = zr[c * 64 + lane];
      const float evv = er[c * 64 + lane];
      const float dv = evv - zv;
      orow[c * 64 + lane] = zv + dv;
      lsum += dv * dv;
    }
    if (lane == 0) out[1 + (size_t)NROWS * DIM + row] = (float)idx;
  }
#pragma unroll
  for (int off = 32; off > 0; off >>= 1) lsum += __shfl_down(lsum, off);
  if (lane == 0) atomicAdd(loss_acc, lsum);
}

// ==========================================================================
extern "C" void kernel_launch(void* const* d_in, const int* in_sizes, int n_in,
                              void* d_out, int out_size, void* d_ws, size_t ws_size,
                              hipStream_t stream) {
  const float* z   = (const float*)d_in[0];
  const float* emb = (const float*)d_in[1];
  float* out = (float*)d_out;
  char*  ws  = (char*)d_ws;

  if (ws_size >= WB_NEED) {
    u16*   zh   = (u16*)(ws + WB_ZHI);
    u16*   zl   = (u16*)(ws + WB_ZLO);
    u16*   eh   = (u16*)(ws + WB_EHI);
    u16*   el   = (u16*)(ws + WB_ELO);
    float* te   = (float*)(ws + WB_TE);
    f32x4* top2 = (f32x4*)(ws + WB_TOP2);
    float* lossum = (float*)(ws + WB_LOSS);

    hipMemsetAsync(lossum, 0, sizeof(float), stream);
    vq_split<<<(NROWS / 16) * KT / 4, 256, 0, stream>>>(z, zh, zl, (NROWS / 16) * KT);
    vq_split<<<(NCODES / 16) * KT / 4, 256, 0, stream>>>(emb, eh, el, (NCODES / 16) * KT);
    vq_rownorm<<<NCODES / 4, 256, 0, stream>>>(emb, te, NCODES);
    vq_mfma_top2<<<dim3(NROWS / BM, NSPLIT), 256, 0, stream>>>(zh, zl, eh, el, te, top2);
    vq_rescore_out<<<NROWS / 4, 256, 0, stream>>>(z, emb, te, top2, out, lossum);
    vq_finalize<<<1, 64, 0, stream>>>(lossum, out);
  } else {
    float* fws = (float*)d_ws;
    float* s_z = fws + FW_S;
    float* t_e = fws + FW_T;
    float* bestd = fws + FW_BD;
    int*   besti = (int*)(fws + FW_BI);
    float* lossum = fws + FW_LOSS;

    hipMemsetAsync(lossum, 0, sizeof(float), stream);
    vq_rownorm<<<NROWS / 4, 256, 0, stream>>>(z, s_z, NROWS);
    vq_rownorm<<<NCODES / 4, 256, 0, stream>>>(emb, t_e, NCODES);
    vq_argmin_fb<<<dim3(NROWS / 64, 2), 256, 0, stream>>>(z, emb, s_z, t_e, bestd, besti);
    vq_gather_fb<<<2048, 256, 0, stream>>>(z, emb, bestd, besti, out, lossum);
    vq_finalize<<<1, 64, 0, stream>>>(lossum, out);
  }
}

// Round 3
// 481.441 us; speedup vs baseline: 9.6998x; 2.9749x over previous
//
#include <hip/hip_runtime.h>

typedef unsigned short u16;
typedef __attribute__((ext_vector_type(8))) short short8;
typedef __attribute__((ext_vector_type(4))) float f32x4;
typedef __attribute__((ext_vector_type(8))) u16 u16x8;

#define NROWS 32768
#define NCODES 8192
#define DIM 512
#define KT 16                     // 512 / 32

// GEMM geometry: BM=256 (4 waves x 64 rows), BN=128, BK=32
#define BM 256
#define BN 128
#define NSPLIT 8
#define NT (NCODES / NSPLIT / BN)   // 8 col tiles per block

// workspace byte offsets
#define WB_ZH  ((size_t)0)                                // bf16 z, fragment order
#define WB_EH  (WB_ZH + (size_t)NROWS * DIM * 2)          // bf16 emb
#define WB_TE  (WB_EH + (size_t)NCODES * DIM * 2)         // fp32 ||e||^2
#define WB_K4  (WB_TE + (size_t)NCODES * 4)               // [NSPLIT][NROWS] int4 top4 keys
#define WB_SSQ (WB_K4 + (size_t)NSPLIT * NROWS * 16)      // [NROWS] fp32 row ssq
#define WB_NEED (WB_SSQ + (size_t)NROWS * 4 + 64)

__device__ __forceinline__ u16 f2bf(float x) {
  unsigned u = __float_as_uint(x);
  u += 0x7FFFu + ((u >> 16) & 1u);   // RNE; inputs finite
  return (u16)(u >> 16);
}
__device__ __forceinline__ void gld16(const void* g, void* l) {
  __builtin_amdgcn_global_load_lds(
      (const __attribute__((address_space(1))) void*)g,
      (__attribute__((address_space(3))) void*)l, 16, 0, 0);
}

// ---------------------------------------------------------------- row norms
__global__ void vq_rownorm(const float* __restrict__ x, float* __restrict__ out,
                           int nrows) {
  int gid  = blockIdx.x * blockDim.x + threadIdx.x;
  int w    = gid >> 6;
  int lane = gid & 63;
  if (w >= nrows) return;
  const float4* row = (const float4*)(x + (size_t)w * DIM);
  float4 a = row[lane];
  float4 b = row[lane + 64];
  float s = a.x * a.x + a.y * a.y + a.z * a.z + a.w * a.w
          + b.x * b.x + b.y * b.y + b.z * b.z + b.w * b.w;
#pragma unroll
  for (int off = 32; off > 0; off >>= 1) s += __shfl_down(s, off);
  if (lane == 0) out[w] = s;
}

// -------------------------------------------- fp32 -> bf16 fragment chunks
// chunk layout: [g (16-row group)][kt][lane][8 bf16], lane = kgrp*16 + row%16
__global__ void vq_tobf16(const float* __restrict__ x, u16* __restrict__ hi,
                          int nwaves) {
  int W = blockIdx.x * (blockDim.x >> 6) + (threadIdx.x >> 6);
  if (W >= nwaves) return;
  int lane = threadIdx.x & 63;
  int g = W >> 4, kt = W & (KT - 1);
  int row = g * 16 + (lane & 15);
  int k0  = kt * 32 + (lane >> 4) * 8;
  const float* src = x + (size_t)row * DIM + k0;
  f32x4 a = *(const f32x4*)src;
  f32x4 b = *(const f32x4*)(src + 4);
  float v[8] = {a[0], a[1], a[2], a[3], b[0], b[1], b[2], b[3]};
  u16x8 h;
#pragma unroll
  for (int j = 0; j < 8; ++j) h[j] = f2bf(v[j]);
  *(u16x8*)(hi + ((size_t)W * 64 + lane) * 8) = h;
}

// ------------------- 1-pass bf16 MFMA distance ranking, per-split top4 keys
// key = trunc((te - 2*dot)*2048)*8192 + col  (monotone lex in (d-bucket, col))
__global__ __launch_bounds__(256, 2) void vq_mfma_top4(
    const u16* __restrict__ zh, const u16* __restrict__ eh,
    const float* __restrict__ te, int4* __restrict__ k4) {
  __shared__ __align__(16) u16 lds[12288];   // Ah 16KB | Bh 8KB (dump reuses)
  u16* Ah = lds;                             // [16 grp][512]
  u16* Bh = lds + 8192;                      // [8 grp][512]

  const int tid   = threadIdx.x;
  const int w     = tid >> 6;
  const int lane  = tid & 63;
  const int bx    = blockIdx.x;              // row tile
  const int split = blockIdx.y;
  const int cb    = split * (NT * BN);

  const size_t laneoff = (size_t)lane * 8;
  const u16* pa = zh + ((size_t)(bx * 16 + w * 4) * KT) * 512 + laneoff;

  int k1[16], k2[16];
#pragma unroll
  for (int s = 0; s < 16; ++s) { k1[s] = 0x7fffffff; k2[s] = 0x7fffffff; }

  for (int nt = 0; nt < NT; ++nt) {
    const int col0 = cb + nt * BN;
    const u16* pb = eh + ((size_t)(col0 >> 4) * KT) * 512 + laneoff;

    float tv2[8];
#pragma unroll
    for (int n = 0; n < 8; ++n) tv2[n] = te[col0 + n * 16 + (lane & 15)] * 2048.0f;

    f32x4 acc[4][8];
#pragma unroll
    for (int m = 0; m < 4; ++m)
#pragma unroll
      for (int n = 0; n < 8; ++n) acc[m][n] = (f32x4){0.f, 0.f, 0.f, 0.f};

    for (int kt = 0; kt < KT; ++kt) {
      __syncthreads();   // protect previous iteration's LDS reads
#pragma unroll
      for (int j = 0; j < 4; ++j)
        gld16(pa + ((size_t)(j * KT + kt)) * 512, Ah + (w * 4 + j) * 512);
#pragma unroll
      for (int j = 0; j < 2; ++j)
        gld16(pb + ((size_t)((2 * w + j) * KT + kt)) * 512, Bh + (2 * w + j) * 512);
      __syncthreads();

      short8 a[4];
#pragma unroll
      for (int m = 0; m < 4; ++m)
        a[m] = *(const short8*)(Ah + (w * 4 + m) * 512 + lane * 8);
#pragma unroll
      for (int n = 0; n < 8; ++n) {
        const short8 b = *(const short8*)(Bh + n * 512 + lane * 8);
#pragma unroll
        for (int m = 0; m < 4; ++m)
          acc[m][n] = __builtin_amdgcn_mfma_f32_16x16x32_bf16(a[m], b, acc[m][n], 0, 0, 0);
      }
    }

    // branchless per-thread top2 fold (6 VALU / candidate)
#pragma unroll
    for (int m = 0; m < 4; ++m)
#pragma unroll
      for (int n = 0; n < 8; ++n) {
        const int col = col0 + n * 16 + (lane & 15);
#pragma unroll
        for (int q = 0; q < 4; ++q) {
          const float kf = fmaf(acc[m][n][q], -4096.0f, tv2[n]);
          const int ki = (int)kf;
          const int key = (int)((unsigned)ki << 13) + col;
          const int s = m * 4 + q;
          const int hi = max(k1[s], key);
          k1[s] = min(k1[s], key);
          k2[s] = min(k2[s], hi);
        }
      }
  }

  // two-phase dump + per-row top4 scan (rows 0-127, then 128-255 of block)
  int* dump = (int*)lds;   // [128 rows][16 lanes][2] = 16KB
#pragma unroll
  for (int phase = 0; phase < 2; ++phase) {
    __syncthreads();
#pragma unroll
    for (int m2 = 0; m2 < 2; ++m2) {
      const int m = phase * 2 + m2;
#pragma unroll
      for (int q = 0; q < 4; ++q) {
        const int s = m * 4 + q;
        const int r128 = w * 32 + m2 * 16 + (lane >> 4) * 4 + q;
        dump[(r128 * 16 + (lane & 15)) * 2 + 0] = k1[s];
        dump[(r128 * 16 + (lane & 15)) * 2 + 1] = k2[s];
      }
    }
    __syncthreads();
    if (tid < 128) {
      int t0 = 0x7fffffff, t1 = 0x7fffffff, t2 = 0x7fffffff, t3 = 0x7fffffff;
#pragma unroll
      for (int j = 0; j < 32; ++j) {
        int k = dump[tid * 32 + j];
        int x;
        x = min(t0, k); k = max(t0, k); t0 = x;
        x = min(t1, k); k = max(t1, k); t1 = x;
        x = min(t2, k); k = max(t2, k); t2 = x;
        t3 = min(t3, k);
      }
      const int row = bx * BM + (tid >> 5) * 64 + phase * 32 + (tid & 31);
      k4[(size_t)split * NROWS + row] = make_int4(t0, t1, t2, t3);
    }
  }
}

// ------------- merge 8x4 keys -> global top8, exact fp32 rescore, output
__global__ void vq_rescore8(const float* __restrict__ z, const float* __restrict__ emb,
                            const float* __restrict__ te, const int4* __restrict__ k4,
                            float* __restrict__ out, float* __restrict__ rowssq) {
  const int row  = (blockIdx.x * blockDim.x + threadIdx.x) >> 6;
  const int lane = threadIdx.x & 63;
  if (row >= NROWS) return;

  int t[8];
#pragma unroll
  for (int j = 0; j < 8; ++j) t[j] = 0x7fffffff;
#pragma unroll
  for (int s = 0; s < NSPLIT; ++s) {
    const int4 kk = k4[(size_t)s * NROWS + row];
    int c[4] = {kk.x, kk.y, kk.z, kk.w};
#pragma unroll
    for (int u = 0; u < 4; ++u) {
      int k = c[u];
#pragma unroll
      for (int j = 0; j < 8; ++j) {
        const int lo = min(t[j], k);
        k = max(t[j], k);
        t[j] = lo;
      }
    }
  }

  int idx[8];
#pragma unroll
  for (int c = 0; c < 8; ++c) idx[c] = t[c] & 8191;

  const f32x4* zr = (const f32x4*)(z + (size_t)row * DIM);
  const f32x4 za = zr[lane], zb = zr[lane + 64];

  f32x4 ea[8], eb[8];
#pragma unroll
  for (int c = 0; c < 8; ++c) {
    const f32x4* er = (const f32x4*)(emb + (size_t)idx[c] * DIM);
    ea[c] = er[lane];
    eb[c] = er[lane + 64];
  }

  float sp = za[0] * za[0] + za[1] * za[1] + za[2] * za[2] + za[3] * za[3]
           + zb[0] * zb[0] + zb[1] * zb[1] + zb[2] * zb[2] + zb[3] * zb[3];
  float p[8];
#pragma unroll
  for (int c = 0; c < 8; ++c)
    p[c] = za[0] * ea[c][0] + za[1] * ea[c][1] + za[2] * ea[c][2] + za[3] * ea[c][3]
         + zb[0] * eb[c][0] + zb[1] * eb[c][1] + zb[2] * eb[c][2] + zb[3] * eb[c][3];

#pragma unroll
  for (int off = 32; off > 0; off >>= 1) {
    sp += __shfl_down(sp, off);
#pragma unroll
    for (int c = 0; c < 8; ++c) p[c] += __shfl_down(p[c], off);
  }
  sp = __shfl(sp, 0);
#pragma unroll
  for (int c = 0; c < 8; ++c) p[c] = __shfl(p[c], 0);

  float bd = (sp + te[idx[0]]) - 2.0f * p[0];
  int   bi = idx[0];
  f32x4 ga = ea[0], gb = eb[0];
#pragma unroll
  for (int c = 1; c < 8; ++c) {
    const float d = (sp + te[idx[c]]) - 2.0f * p[c];
    const bool better = (d < bd) || (d == bd && idx[c] < bi);
    if (better) { bd = d; bi = idx[c]; ga = ea[c]; gb = eb[c]; }
  }

  float* orow = out + 1 + (size_t)row * DIM;
  float lsum = 0.f;
#pragma unroll
  for (int j = 0; j < 4; ++j) {
    const float dv = ga[j] - za[j];
    orow[4 * lane + j] = za[j] + dv;
    lsum += dv * dv;
    const float dw = gb[j] - zb[j];
    orow[256 + 4 * lane + j] = zb[j] + dw;
    lsum += dw * dw;
  }
#pragma unroll
  for (int off = 32; off > 0; off >>= 1) lsum += __shfl_down(lsum, off);
  if (lane == 0) {
    rowssq[row] = lsum;
    out[1 + (size_t)NROWS * DIM + row] = (float)bi;
  }
}

// ----------------------------- single-block loss reduction (no atomics)
__global__ void vq_finalize(const float* __restrict__ rowssq, float* __restrict__ out) {
  __shared__ float red[16];
  float s = 0.f;
  for (int i = threadIdx.x; i < NROWS; i += 1024) s += rowssq[i];
#pragma unroll
  for (int off = 32; off > 0; off >>= 1) s += __shfl_down(s, off);
  if ((threadIdx.x & 63) == 0) red[threadIdx.x >> 6] = s;
  __syncthreads();
  if (threadIdx.x < 64) {
    float v = (threadIdx.x < 16) ? red[threadIdx.x] : 0.f;
#pragma unroll
    for (int off = 32; off > 0; off >>= 1) v += __shfl_down(v, off);
    if (threadIdx.x == 0) {
      const float m = v / 16777216.0f;   // mean over N*D = 2^24 (exact)
      out[0] = m + m;                    // (1 + BETA) * m
    }
  }
}

// ==========================================================================
extern "C" void kernel_launch(void* const* d_in, const int* in_sizes, int n_in,
                              void* d_out, int out_size, void* d_ws, size_t ws_size,
                              hipStream_t stream) {
  const float* z   = (const float*)d_in[0];
  const float* emb = (const float*)d_in[1];
  float* out = (float*)d_out;
  char*  ws  = (char*)d_ws;

  u16*   zh  = (u16*)(ws + WB_ZH);
  u16*   eh  = (u16*)(ws + WB_EH);
  float* te  = (float*)(ws + WB_TE);
  int4*  k4  = (int4*)(ws + WB_K4);
  float* ssq = (float*)(ws + WB_SSQ);

  vq_tobf16<<<(NROWS / 16) * KT / 4, 256, 0, stream>>>(z, zh, (NROWS / 16) * KT);
  vq_tobf16<<<(NCODES / 16) * KT / 4, 256, 0, stream>>>(emb, eh, (NCODES / 16) * KT);
  vq_rownorm<<<NCODES / 4, 256, 0, stream>>>(emb, te, NCODES);

  vq_mfma_top4<<<dim3(NROWS / BM, NSPLIT), 256, 0, stream>>>(zh, eh, te, k4);

  vq_rescore8<<<NROWS / 4, 256, 0, stream>>>(z, emb, te, k4, out, ssq);
  vq_finalize<<<1, 1024, 0, stream>>>(ssq, out);
}